// Round 1
// baseline (778.890 us; speedup 1.0000x reference)
//
#include <hip/hip_runtime.h>
#include <math.h>

typedef __attribute__((ext_vector_type(8))) short bshort8;
typedef __attribute__((ext_vector_type(4))) float f32x4;

#define DI __device__ __forceinline__

DI unsigned short f2bf(float x) {
    unsigned int u = __builtin_bit_cast(unsigned int, x);
    u += 0x7fffu + ((u >> 16) & 1u);
    return (unsigned short)(u >> 16);
}

DI bshort8 pack8(const float* v) {
    bshort8 r;
    #pragma unroll
    for (int j = 0; j < 8; j++) r[j] = (short)f2bf(v[j]);
    return r;
}

DI f32x4 mfma16(bshort8 a, bshort8 b, f32x4 c) {
    return __builtin_amdgcn_mfma_f32_16x16x32_bf16(a, b, c, 0, 0, 0);
}

// ---- composite (bilinear resize N->112, align_corners=False) + 8x8 avgpool stencils ----
__device__ const float W14[14][3] = {
    {0.875f, 0.125f, 0.f},
    {0.125f, 0.75f, 0.125f}, {0.125f, 0.75f, 0.125f}, {0.125f, 0.75f, 0.125f},
    {0.125f, 0.75f, 0.125f}, {0.125f, 0.75f, 0.125f}, {0.125f, 0.75f, 0.125f},
    {0.125f, 0.75f, 0.125f}, {0.125f, 0.75f, 0.125f}, {0.125f, 0.75f, 0.125f},
    {0.125f, 0.75f, 0.125f}, {0.125f, 0.75f, 0.125f}, {0.125f, 0.75f, 0.125f},
    {0.125f, 0.875f, 0.f}};
__device__ const float W28[14][4] = {
    {0.5f, 0.4375f, 0.0625f, 0.f},
    {0.0625f, 0.4375f, 0.4375f, 0.0625f}, {0.0625f, 0.4375f, 0.4375f, 0.0625f},
    {0.0625f, 0.4375f, 0.4375f, 0.0625f}, {0.0625f, 0.4375f, 0.4375f, 0.0625f},
    {0.0625f, 0.4375f, 0.4375f, 0.0625f}, {0.0625f, 0.4375f, 0.4375f, 0.0625f},
    {0.0625f, 0.4375f, 0.4375f, 0.0625f}, {0.0625f, 0.4375f, 0.4375f, 0.0625f},
    {0.0625f, 0.4375f, 0.4375f, 0.0625f}, {0.0625f, 0.4375f, 0.4375f, 0.0625f},
    {0.0625f, 0.4375f, 0.4375f, 0.0625f}, {0.0625f, 0.4375f, 0.4375f, 0.0625f},
    {0.0625f, 0.4375f, 0.5f, 0.f}};
__device__ const float W56[14][6] = {
    {0.25f, 0.25f, 0.25f, 0.21875f, 0.03125f, 0.f},
    {0.03125f, 0.21875f, 0.25f, 0.25f, 0.21875f, 0.03125f},
    {0.03125f, 0.21875f, 0.25f, 0.25f, 0.21875f, 0.03125f},
    {0.03125f, 0.21875f, 0.25f, 0.25f, 0.21875f, 0.03125f},
    {0.03125f, 0.21875f, 0.25f, 0.25f, 0.21875f, 0.03125f},
    {0.03125f, 0.21875f, 0.25f, 0.25f, 0.21875f, 0.03125f},
    {0.03125f, 0.21875f, 0.25f, 0.25f, 0.21875f, 0.03125f},
    {0.03125f, 0.21875f, 0.25f, 0.25f, 0.21875f, 0.03125f},
    {0.03125f, 0.21875f, 0.25f, 0.25f, 0.21875f, 0.03125f},
    {0.03125f, 0.21875f, 0.25f, 0.25f, 0.21875f, 0.03125f},
    {0.03125f, 0.21875f, 0.25f, 0.25f, 0.21875f, 0.03125f},
    {0.03125f, 0.21875f, 0.25f, 0.25f, 0.21875f, 0.03125f},
    {0.03125f, 0.21875f, 0.25f, 0.25f, 0.21875f, 0.03125f},
    {0.03125f, 0.21875f, 0.25f, 0.25f, 0.25f, 0.f}};

// -------- pooled-feature bodies; pf layout [cin][1568], col = b*196 + r --------
template <int N, int C, int TAPS>
DI void pool_body(const float* __restrict__ src, float* __restrict__ dst,
                  unsigned blk, unsigned t)
{
    unsigned id = blk * 256u + t;
    unsigned p = id / 196u;
    unsigned r = id - p * 196u;
    unsigned ti = r / 14u, tj = r - ti * 14u;
    unsigned b = p / C, cin = p - b * C;
    const float* plane = src + (size_t)p * (N * N);
    float acc = 0.f;
    if constexpr (N == 112) {
        const float4* p4 = (const float4*)(plane + (size_t)(ti * 8) * 112 + tj * 8);
        #pragma unroll
        for (int i = 0; i < 8; i++) {
            float4 u = p4[i * 28];
            float4 v = p4[i * 28 + 1];
            acc += (u.x + u.y) + (u.z + u.w) + (v.x + v.y) + (v.z + v.w);
        }
        acc *= (1.f / 64.f);
    } else {
        constexpr int STRIDE = N / 14;
        const float (*WT)[TAPS] = (N == 14) ? (const float (*)[TAPS])W14
                                : (N == 28) ? (const float (*)[TAPS])W28
                                            : (const float (*)[TAPS])W56;
        int hs = (int)(STRIDE * ti) - 1; if (hs < 0) hs = 0;
        int ws = (int)(STRIDE * tj) - 1; if (ws < 0) ws = 0;
        float wh[TAPS], ww[TAPS];
        #pragma unroll
        for (int i = 0; i < TAPS; i++) { wh[i] = WT[ti][i]; ww[i] = WT[tj][i]; }
        #pragma unroll
        for (int i = 0; i < TAPS; i++) {
            int hi = hs + i; if (hi > N - 1) hi = N - 1;
            const float* row = plane + (size_t)hi * N;
            float rs = 0.f;
            #pragma unroll
            for (int j = 0; j < TAPS; j++) {
                int wj = ws + j; if (wj > N - 1) wj = N - 1;
                rs += ww[j] * row[wj];
            }
            acc += wh[i] * rs;
        }
    }
    dst[(size_t)cin * 1568 + b * 196 + r] = acc;
}

DI void c5_mean_body(const float* __restrict__ c5, float* __restrict__ pooled,
                     unsigned blk, unsigned t)
{
    int wid = t >> 6, lane = t & 63;
    int p = blk * 4 + wid;
    const float* plane = c5 + (size_t)p * 196;
    float v = plane[lane] + plane[64 + lane] + plane[128 + lane];
    if (lane < 4) v += plane[192 + lane];
    #pragma unroll
    for (int off = 32; off > 0; off >>= 1) v += __shfl_xor(v, off, 64);
    if (lane == 0) pooled[p] = v * (1.f / 196.f);
}

// -------- K1: all four scale pools + c5 mean in ONE dispatch (block-range split) --------
// grid: 1568 + 3136 + 6272 + 12544 + 4096 = 27616 blocks
__global__ __launch_bounds__(256) void pool_all(
    const float* __restrict__ c2, const float* __restrict__ c3,
    const float* __restrict__ c4, const float* __restrict__ c5,
    float* __restrict__ pf0, float* __restrict__ pf1,
    float* __restrict__ pf2, float* __restrict__ pf3,
    float* __restrict__ pooled, unsigned* __restrict__ bar)
{
    unsigned bx = blockIdx.x, t = threadIdx.x;
    if (bx == 27615u && t < 8u) bar[t] = 0u;   // zero grid-barrier counters for tail_coop
    if (bx < 1568u)       pool_body<112, 256, 8>(c2, pf0, bx, t);
    else if (bx < 4704u)  pool_body<56, 512, 6>(c3, pf1, bx - 1568u, t);
    else if (bx < 10976u) pool_body<28, 1024, 4>(c4, pf2, bx - 4704u, t);
    else if (bx < 23520u) pool_body<14, 2048, 3>(c5, pf3, bx - 10976u, t);
    else                  c5_mean_body(c5, pooled, bx - 23520u, t);
}

// -------- K2a: partial GEMV for scale-weight MLP layer 1 (split-K) --------
__global__ __launch_bounds__(512) void sw_part(
    const float* __restrict__ pooled, const float* __restrict__ sp_w1,
    float* __restrict__ partial)
{
    int b = blockIdx.x, kc = blockIdx.y, t = threadIdx.x;
    __shared__ float ps[256];
    if (t < 256) ps[t] = pooled[b * 2048 + kc * 256 + t];
    __syncthreads();
    float acc = 0.f;
    const float* w = sp_w1 + (size_t)(kc * 256) * 512 + t;
    #pragma unroll 8
    for (int c = 0; c < 256; c++) acc += ps[c] * w[(size_t)c * 512];
    partial[((size_t)b * 8 + kc) * 512 + t] = acc;
}

// -------- K2b: finish sw MLP + write bias-initialized xtok (absorbs xtok_init) --------
__global__ __launch_bounds__(512) void sw_fin(
    const float* __restrict__ partial, const float* __restrict__ sp_b1,
    const float* __restrict__ sp_w2, const float* __restrict__ sp_b2,
    const float* __restrict__ lb0, const float* __restrict__ lb1,
    const float* __restrict__ lb2, const float* __restrict__ lb3,
    float* __restrict__ sw_out, float* __restrict__ xtok)
{
    int b = blockIdx.x, t = threadIdx.x;
    __shared__ float h[512];
    __shared__ float s4s[4];
    __shared__ float swl[4];
    __shared__ float bf_s[256];
    float a = sp_b1[t];
    #pragma unroll
    for (int kc = 0; kc < 8; kc++) a += partial[((size_t)b * 8 + kc) * 512 + t];
    h[t] = fmaxf(a, 0.f);
    __syncthreads();
    int wv = t >> 6, lane = t & 63;
    if (wv < 4) {
        float acc = 0.f;
        #pragma unroll
        for (int i = 0; i < 8; i++) {
            int idx = lane + 64 * i;
            acc += h[idx] * sp_w2[idx * 4 + wv];
        }
        #pragma unroll
        for (int off = 32; off > 0; off >>= 1) acc += __shfl_xor(acc, off, 64);
        if (lane == 0) s4s[wv] = acc + sp_b2[wv];
    }
    __syncthreads();
    if (t == 0) {
        float mx = fmaxf(fmaxf(s4s[0], s4s[1]), fmaxf(s4s[2], s4s[3]));
        float e0 = expf(s4s[0] - mx), e1 = expf(s4s[1] - mx);
        float e2 = expf(s4s[2] - mx), e3 = expf(s4s[3] - mx);
        float inv = 1.f / (e0 + e1 + e2 + e3);
        swl[0] = e0 * inv; swl[1] = e1 * inv; swl[2] = e2 * inv; swl[3] = e3 * inv;
        for (int o = 0; o < 4; o++) sw_out[b * 4 + o] = swl[o];
    }
    __syncthreads();
    if (t < 256)
        bf_s[t] = swl[0] * lb0[t] + swl[1] * lb1[t] + swl[2] * lb2[t] + swl[3] * lb3[t];
    __syncthreads();
    int c = t & 255, half = t >> 8;
    float bv = bf_s[c];
    float* xb = xtok + (size_t)b * 196 * 256 + c;
    for (int r = half; r < 196; r += 2) xb[(size_t)r * 256] = bv;
}

// -------- K3: lateral projection, fragment-direct staging, split into 8 K-slices --------
__global__ __launch_bounds__(256) void lateral_slice(
    const float* __restrict__ pf0, const float* __restrict__ pf1,
    const float* __restrict__ pf2, const float* __restrict__ pf3,
    const float* __restrict__ w0, const float* __restrict__ w1,
    const float* __restrict__ w2, const float* __restrict__ w3,
    const float* __restrict__ sw, float* __restrict__ xtok)
{
    const int sArr[8]    = {0, 1, 2, 2, 3, 3, 3, 3};
    const int koffArr[8] = {0, 0, 0, 512, 0, 512, 1024, 1536};
    const int klenArr[8] = {256, 512, 512, 512, 512, 512, 512, 512};
    int sl = blockIdx.y;
    int s = sArr[sl], koff = koffArr[sl], klen = klenArr[sl];
    const float* pf = (s == 0) ? pf0 : (s == 1) ? pf1 : (s == 2) ? pf2 : pf3;
    const float* W  = (s == 0) ? w0  : (s == 1) ? w1  : (s == 2) ? w2  : w3;

    int mt = blockIdx.x % 49, nt = blockIdx.x / 49;
    int m0 = mt * 32, n0 = nt * 64;
    __shared__ alignas(16) unsigned short As[1024];
    __shared__ alignas(16) unsigned short Bs[2048];
    int t = threadIdx.x, lane = t & 63, wid = t >> 6;
    int wm = wid >> 1, wn = wid & 1;
    f32x4 acc0 = {0, 0, 0, 0}, acc1 = {0, 0, 0, 0};

    int f = t & 63;
    int mA = m0 + ((t >> 6) & 1) * 16 + (f & 15);   // t<128
    int kbA = (f >> 4) * 8;
    int nB = n0 + (t >> 6) * 16 + (f & 15);
    int kbB = (f >> 4) * 8;
    float swv = sw[(mA / 196) * 4 + s];

    float ar[8], br[8];
    auto loadA = [&](int k0) {
        if (t < 128) {
            const float* base = pf + (size_t)(koff + k0 + kbA) * 1568 + mA;
            #pragma unroll
            for (int j = 0; j < 8; j++) ar[j] = base[(size_t)j * 1568] * swv;
        }
    };
    auto loadB = [&](int k0) {
        const float* base = W + (size_t)(koff + k0 + kbB) * 256 + nB;
        #pragma unroll
        for (int j = 0; j < 8; j++) br[j] = base[(size_t)j * 256];
    };

    loadA(0); loadB(0);
    for (int k0 = 0; k0 < klen; k0 += 32) {
        if (t < 128) *(bshort8*)&As[(((t >> 6) & 1) * 512 + f * 8)] = pack8(ar);
        *(bshort8*)&Bs[((t >> 6) * 512 + f * 8)] = pack8(br);
        __syncthreads();
        if (k0 + 32 < klen) { loadA(k0 + 32); loadB(k0 + 32); }
        bshort8 av = *(const bshort8*)&As[wm * 512 + lane * 8];
        bshort8 bv0 = *(const bshort8*)&Bs[(wn * 2 + 0) * 512 + lane * 8];
        bshort8 bv1 = *(const bshort8*)&Bs[(wn * 2 + 1) * 512 + lane * 8];
        acc0 = mfma16(av, bv0, acc0);
        acc1 = mfma16(av, bv1, acc1);
        __syncthreads();
    }
    int col0 = n0 + wn * 32 + (lane & 15);
    int rbase = m0 + wm * 16 + ((lane >> 4) << 2);
    #pragma unroll
    for (int r = 0; r < 4; r++) {
        int m = rbase + r;
        atomicAdd(&xtok[(size_t)m * 256 + col0], acc0[r]);
        atomicAdd(&xtok[(size_t)m * 256 + col0 + 16], acc1[r]);
    }
}

// -------- generic bf16-MFMA GEMM, fragment-direct staging + reg prefetch --------
template <bool B_IS_KXN>
__global__ __launch_bounds__(256) void gemm_kernel(
    const float* __restrict__ Ab, int lda, long long sAy, long long sAz,
    const float* __restrict__ Bb, int ldb, long long sBy, long long sBz,
    float* __restrict__ Cb, int ldc, long long sCy, long long sCz,
    const float* __restrict__ bias, int M, int N, int K,
    float alpha, int mtiles)
{
    const float* A = Ab + blockIdx.y * sAy + blockIdx.z * sAz;
    const float* B = Bb + blockIdx.y * sBy + blockIdx.z * sBz;
    float* C = Cb + blockIdx.y * sCy + blockIdx.z * sCz;
    int mt = blockIdx.x % mtiles, nt = blockIdx.x / mtiles;
    int m0 = mt * 32, n0 = nt * 64;
    __shared__ alignas(16) unsigned short As[1024];
    __shared__ alignas(16) unsigned short Bs[2048];
    int t = threadIdx.x, lane = t & 63, wid = t >> 6;
    int wm = wid >> 1, wn = wid & 1;
    f32x4 acc0 = {0, 0, 0, 0}, acc1 = {0, 0, 0, 0};

    int f = t & 63;
    int mA = m0 + ((t >> 6) & 1) * 16 + (f & 15);   // t<128
    int kbA = (f >> 4) * 8;
    int nB = n0 + (t >> 6) * 16 + (f & 15);
    int kbB = (f >> 4) * 8;

    float ar[8], br[8];
    auto loadA = [&](int k0) {
        if (t < 128) {
            int kb = k0 + kbA;
            if (mA < M && kb + 8 <= K) {
                const float4* p = (const float4*)(A + (size_t)mA * lda + kb);
                float4 u = p[0], v = p[1];
                ar[0] = u.x; ar[1] = u.y; ar[2] = u.z; ar[3] = u.w;
                ar[4] = v.x; ar[5] = v.y; ar[6] = v.z; ar[7] = v.w;
            } else {
                #pragma unroll
                for (int j = 0; j < 8; j++) {
                    int k = kb + j;
                    ar[j] = (mA < M && k < K) ? A[(size_t)mA * lda + k] : 0.f;
                }
            }
        }
    };
    auto loadB = [&](int k0) {
        int kb = k0 + kbB;
        if constexpr (B_IS_KXN) {
            #pragma unroll
            for (int j = 0; j < 8; j++) {
                int k = kb + j;
                br[j] = (k < K && nB < N) ? B[(size_t)k * ldb + nB] : 0.f;
            }
        } else {
            if (nB < N && kb + 8 <= K) {
                const float4* p = (const float4*)(B + (size_t)nB * ldb + kb);
                float4 u = p[0], v = p[1];
                br[0] = u.x; br[1] = u.y; br[2] = u.z; br[3] = u.w;
                br[4] = v.x; br[5] = v.y; br[6] = v.z; br[7] = v.w;
            } else {
                #pragma unroll
                for (int j = 0; j < 8; j++) {
                    int k = kb + j;
                    br[j] = (nB < N && k < K) ? B[(size_t)nB * ldb + k] : 0.f;
                }
            }
        }
    };

    loadA(0); loadB(0);
    for (int k0 = 0; k0 < K; k0 += 32) {
        if (t < 128) *(bshort8*)&As[(((t >> 6) & 1) * 512 + f * 8)] = pack8(ar);
        *(bshort8*)&Bs[((t >> 6) * 512 + f * 8)] = pack8(br);
        __syncthreads();
        if (k0 + 32 < K) { loadA(k0 + 32); loadB(k0 + 32); }
        bshort8 av = *(const bshort8*)&As[wm * 512 + lane * 8];
        bshort8 bv0 = *(const bshort8*)&Bs[(wn * 2 + 0) * 512 + lane * 8];
        bshort8 bv1 = *(const bshort8*)&Bs[(wn * 2 + 1) * 512 + lane * 8];
        acc0 = mfma16(av, bv0, acc0);
        acc1 = mfma16(av, bv1, acc1);
        __syncthreads();
    }
    int col0 = n0 + wn * 32 + (lane & 15);
    int rbase = m0 + wm * 16 + ((lane >> 4) << 2);
    #pragma unroll
    for (int r = 0; r < 4; r++) {
        int m = rbase + r;
        if (m < M) {
            if (col0 < N) {
                float v = acc0[r] * alpha;
                if (bias) v += bias[col0];
                C[(size_t)m * ldc + col0] = v;
            }
            int c1 = col0 + 16;
            if (c1 < N) {
                float v = acc1[r] * alpha;
                if (bias) v += bias[c1];
                C[(size_t)m * ldc + c1] = v;
            }
        }
    }
}

// -------- attention softmax over rows of S [12544][196], in place --------
__global__ __launch_bounds__(256) void attn_softmax(float* __restrict__ S)
{
    int wid = threadIdx.x >> 6, lane = threadIdx.x & 63;
    size_t row = (size_t)blockIdx.x * 4 + wid;
    float* p = S + row * 196;
    float v0 = p[lane];
    float v1 = p[64 + lane];
    float v2 = p[128 + lane];
    float v3 = (lane < 4) ? p[192 + lane] : -1e30f;
    float mx = fmaxf(fmaxf(v0, v1), fmaxf(v2, v3));
    #pragma unroll
    for (int off = 32; off > 0; off >>= 1) mx = fmaxf(mx, __shfl_xor(mx, off, 64));
    float e0 = expf(v0 - mx), e1 = expf(v1 - mx), e2 = expf(v2 - mx);
    float e3 = (lane < 4) ? expf(v3 - mx) : 0.f;
    float sum = e0 + e1 + e2 + e3;
    #pragma unroll
    for (int off = 32; off > 0; off >>= 1) sum += __shfl_xor(sum, off, 64);
    float inv = 1.f / sum;
    p[lane] = e0 * inv;
    p[64 + lane] = e1 * inv;
    p[128 + lane] = e2 * inv;
    if (lane < 4) p[192 + lane] = e3 * inv;
}

// ================= tail: single persistent kernel with grid barrier =================

DI void gsync(unsigned* c) {
    __syncthreads();
    if (threadIdx.x == 0) {
        __threadfence();                       // release: publish this block's writes
        atomicAdd(c, 1u);
        while (atomicAdd(c, 0u) < 640u) __builtin_amdgcn_s_sleep(8);
        __threadfence();                       // acquire: invalidate stale cached lines
    }
    __syncthreads();
}

DI void xo_part_body(const float* __restrict__ xo, float* __restrict__ xopart,
                     int b, int g, int t)
{
    const float* base = xo + ((size_t)b * 196 + g * 28) * 256 + t;
    float s = 0.f;
    #pragma unroll
    for (int n = 0; n < 28; n++) s += base[(size_t)n * 256];
    xopart[(b * 7 + g) * 256 + t] = s;
}

DI void wa2_body(const float* __restrict__ gat_W, const float* __restrict__ gat_a,
                 float* __restrict__ Wa, int h, int q, int t)
{
    int w = t >> 6, lane = t & 63;
    __shared__ float a1[256], a2[256];
    a1[t] = gat_a[h * 512 + t];
    a2[t] = gat_a[h * 512 + 256 + t];
    __syncthreads();
    for (int ci = 0; ci < 16; ci++) {
        int c = q * 64 + w * 16 + ci;
        const float* row = gat_W + (size_t)h * 65536 + (size_t)c * 256;
        float p1 = 0.f, p2 = 0.f;
        #pragma unroll
        for (int jj = 0; jj < 4; jj++) {
            float v = row[lane + 64 * jj];
            p1 += v * a1[lane + 64 * jj];
            p2 += v * a2[lane + 64 * jj];
        }
        #pragma unroll
        for (int off = 32; off > 0; off >>= 1) {
            p1 += __shfl_xor(p1, off, 64);
            p2 += __shfl_xor(p2, off, 64);
        }
        if (lane == 0) { Wa[h * 512 + c] = p1; Wa[h * 512 + 256 + c] = p2; }
    }
}

DI void gctx_part_body(const float* __restrict__ xopart, const float* __restrict__ proj_w,
                       float* __restrict__ gpart, int b, int kc, int t)
{
    __shared__ float xm[64];
    if (t < 64) {
        float s = 0.f;
        #pragma unroll
        for (int g = 0; g < 7; g++) s += xopart[(b * 7 + g) * 256 + kc * 64 + t];
        xm[t] = s * (1.f / 196.f);
    }
    __syncthreads();
    float acc = 0.f;
    const float* w = proj_w + (size_t)(kc * 64) * 256 + t;
    #pragma unroll 8
    for (int j = 0; j < 64; j++) acc += xm[j] * w[(size_t)j * 256];
    gpart[(b * 4 + kc) * 256 + t] = acc;
}

DI void lf_s12_body(const float* __restrict__ gpart, const float* __restrict__ proj_b,
                    const float* __restrict__ lemb, const float* __restrict__ Wa,
                    float* __restrict__ lf, float* __restrict__ s12,
                    int l, int b, int t)
{
    int w = t >> 6, lane = t & 63;
    __shared__ float row[256];
    float g = proj_b[t] + gpart[(b * 4 + 0) * 256 + t] + gpart[(b * 4 + 1) * 256 + t]
            + gpart[(b * 4 + 2) * 256 + t] + gpart[(b * 4 + 3) * 256 + t];
    float v = lemb[l * 256 + t] + g;
    lf[((size_t)b * 80 + l) * 256 + t] = v;
    row[t] = v;
    __syncthreads();
    #pragma unroll
    for (int pp = 0; pp < 2; pp++) {
        int pair = w * 2 + pp;
        float p = 0.f;
        #pragma unroll
        for (int jj = 0; jj < 4; jj++) {
            int c = lane + 64 * jj;
            p += row[c] * Wa[pair * 256 + c];
        }
        #pragma unroll
        for (int off = 32; off > 0; off >>= 1) p += __shfl_xor(p, off, 64);
        if (lane == 0) s12[(b * 8 + pair) * 80 + l] = p;
    }
}

DI void gat_rows_body(const float* __restrict__ s12, float* __restrict__ atts,
                      int b, int h, int z, int t)
{
    int w = t >> 6, lane = t & 63;
    int i = z * 4 + w;
    float s1i = s12[(b * 8 + h * 2) * 80 + i];
    const float* s2 = s12 + (b * 8 + h * 2 + 1) * 80;
    float v0 = s1i + s2[lane]; v0 = v0 > 0.f ? v0 : 0.2f * v0;
    float v1 = -1e30f;
    if (lane < 16) { v1 = s1i + s2[64 + lane]; v1 = v1 > 0.f ? v1 : 0.2f * v1; }
    float mx = fmaxf(v0, v1);
    #pragma unroll
    for (int off = 32; off > 0; off >>= 1) mx = fmaxf(mx, __shfl_xor(mx, off, 64));
    float e0 = expf(v0 - mx), e1 = (lane < 16) ? expf(v1 - mx) : 0.f;
    float sum = e0 + e1;
    #pragma unroll
    for (int off = 32; off > 0; off >>= 1) sum += __shfl_xor(sum, off, 64);
    float inv = 1.f / sum;
    float* orow = atts + (size_t)h * 51200 + b * 6400 + i * 80;
    orow[lane] = e0 * inv;
    if (lane < 16) orow[64 + lane] = e1 * inv;
}

// fused: am col-mean + amlf + hm (full K=256, no split) per (b,h)
DI void amlf_hm_body(const float* __restrict__ atts, const float* __restrict__ lf,
                     const float* __restrict__ gat_W, float* __restrict__ hm,
                     int b, int h, int t)
{
    __shared__ float am[80];
    __shared__ float av[256];
    if (t < 80) {
        const float* base = atts + (size_t)h * 51200 + b * 6400 + t;
        float acc = 0.f;
        #pragma unroll 8
        for (int l = 0; l < 80; l++) acc += base[l * 80];
        am[t] = acc * (1.f / 80.f);
    }
    __syncthreads();
    float acc = 0.f;
    const float* lfb = lf + (size_t)b * 80 * 256 + t;
    #pragma unroll 8
    for (int l = 0; l < 80; l++) acc += am[l] * lfb[(size_t)l * 256];
    av[t] = acc;
    __syncthreads();
    float acc2 = 0.f;
    const float* w = gat_W + (size_t)h * 65536 + t;
    #pragma unroll 8
    for (int k = 0; k < 256; k++) acc2 += av[k] * w[(size_t)k * 256];
    hm[(b * 4 + h) * 256 + t] = acc2;
}

DI void as_part_body(const float* __restrict__ hm, const float* __restrict__ out_w,
                     float* __restrict__ aspart, int b, int kc, int t)
{
    __shared__ float hv[64];
    if (t < 64) {
        int hk = kc * 64 + t;
        int h = hk >> 8, c = hk & 255;
        hv[t] = hm[(b * 4 + h) * 256 + c];
    }
    __syncthreads();
    float acc = 0.f;
    const float* w = out_w + (size_t)(kc * 64) * 256 + t;
    #pragma unroll 8
    for (int j = 0; j < 64; j++) acc += hv[j] * w[(size_t)j * 256];
    aspart[(b * 16 + kc) * 256 + t] = acc;
}

// fused: a_s finalize + mlp1 + mlp2 + final combine, one block per b
DI void fin_body(const float* __restrict__ aspart, const float* __restrict__ out_b,
                 const float* __restrict__ spec_w1, const float* __restrict__ spec_b1,
                 const float* __restrict__ spec_w2, const float* __restrict__ spec_b2,
                 const float* __restrict__ spat_w1, const float* __restrict__ spat_b1,
                 const float* __restrict__ spat_w2, const float* __restrict__ spat_b2,
                 const float* __restrict__ gate_w, const float* __restrict__ gate_b,
                 const float* __restrict__ unc_w, const float* __restrict__ unc_b,
                 float* __restrict__ out, int b, int t)
{
    __shared__ float as_s[256];
    __shared__ float hb[256];      // [0:128)=spec hidden, [128:256)=spat hidden
    __shared__ float fvs[320];
    float a = out_b[t];
    #pragma unroll
    for (int kc = 0; kc < 16; kc++) a += aspart[(b * 16 + kc) * 256 + t];
    as_s[t] = a;
    __syncthreads();
    {
        int which = t >> 7, oo = t & 127;
        const float* w1 = which ? spat_w1 : spec_w1;
        const float* b1 = which ? spat_b1 : spec_b1;
        float acc = b1[oo];
        #pragma unroll 8
        for (int k = 0; k < 256; k++) acc += as_s[k] * w1[(size_t)k * 128 + oo];
        hb[t] = fmaxf(acc, 0.f);
    }
    __syncthreads();
    for (int oi = t; oi < 320; oi += 256) {
        int head = oi / 80, o = oi - head * 80;
        float acc;
        if (head == 0) {
            acc = spec_b2[o];
            #pragma unroll 8
            for (int k = 0; k < 128; k++) acc += hb[k] * spec_w2[(size_t)k * 80 + o];
        } else if (head == 1) {
            acc = spat_b2[o];
            #pragma unroll 8
            for (int k = 0; k < 128; k++) acc += hb[128 + k] * spat_w2[(size_t)k * 80 + o];
        } else if (head == 2) {
            acc = gate_b[o];
            #pragma unroll 8
            for (int k = 0; k < 256; k++) acc += as_s[k] * gate_w[(size_t)k * 80 + o];
        } else {
            acc = unc_b[o];
            #pragma unroll 8
            for (int k = 0; k < 256; k++) acc += as_s[k] * unc_w[(size_t)k * 80 + o];
        }
        fvs[oi] = acc;
    }
    __syncthreads();
    if (t < 80) {
        float sp = fvs[t], st = fvs[80 + t], gz = fvs[160 + t], uz = fvs[240 + t];
        float g = 1.f / (1.f + expf(-gz));
        out[b * 80 + t] = g * sp + (1.f - g) * st;
        out[640 + b * 80 + t] = sp;
        out[1280 + b * 80 + t] = st;
        out[1920 + b * 80 + t] = g;
        as_s[t] = log1pf(expf(uz)) + 1.f;   // reuse as_s for alpha
    }
    __syncthreads();
    if (t == 0) {
        float s = 0.f;
        for (int l = 0; l < 80; l++) s += as_s[l];
        out[2560 + b] = 80.f / s;
    }
}

// 640 blocks x 256 threads; __launch_bounds__(256,4) => >=4 resident blocks/CU
// (VGPR<=128, LDS ~8.3 KB static) so all 640 blocks are co-resident for gsync.
__global__ __launch_bounds__(256, 4) void tail_coop(
    const float* __restrict__ xo, const float* __restrict__ proj_w,
    const float* __restrict__ proj_b,
    const float* __restrict__ gat_W, const float* __restrict__ gat_a,
    const float* __restrict__ lemb,
    const float* __restrict__ out_w, const float* __restrict__ out_b,
    const float* __restrict__ spec_w1, const float* __restrict__ spec_b1,
    const float* __restrict__ spec_w2, const float* __restrict__ spec_b2,
    const float* __restrict__ spat_w1, const float* __restrict__ spat_b1,
    const float* __restrict__ spat_w2, const float* __restrict__ spat_b2,
    const float* __restrict__ gate_w, const float* __restrict__ gate_b,
    const float* __restrict__ unc_w, const float* __restrict__ unc_b,
    float* __restrict__ xopart, float* __restrict__ gpart, float* __restrict__ Wa,
    float* __restrict__ lf, float* __restrict__ s12, float* __restrict__ atts,
    float* __restrict__ hm, float* __restrict__ aspart, float* __restrict__ out,
    unsigned* __restrict__ bar)
{
    int blk = blockIdx.x, t = threadIdx.x;
    // P0: xo token-sum partials (56 blocks) + Wa projections (16 blocks)
    if (blk < 56) xo_part_body(xo, xopart, blk & 7, blk >> 3, t);
    else if (blk < 72) wa2_body(gat_W, gat_a, Wa, (blk - 56) & 3, (blk - 56) >> 2, t);
    gsync(bar + 0);
    // P1: gctx split-K partials (32 blocks)
    if (blk < 32) gctx_part_body(xopart, proj_w, gpart, blk & 7, blk >> 3, t);
    gsync(bar + 1);
    // P2: lf + GAT scores (640 blocks)
    lf_s12_body(gpart, proj_b, lemb, Wa, lf, s12, blk % 80, blk / 80, t);
    gsync(bar + 2);
    // P3: GAT row softmax -> atts (640 blocks)
    gat_rows_body(s12, atts, blk & 7, (blk >> 3) & 3, blk >> 5, t);
    gsync(bar + 3);
    // P4: attention-mean + amlf + hm, fused per (b,h) (32 blocks)
    if (blk < 32) amlf_hm_body(atts, lf, gat_W, hm, blk & 7, blk >> 3, t);
    gsync(bar + 4);
    // P5: a_s split-K partials (128 blocks)
    if (blk < 128) as_part_body(hm, out_w, aspart, blk & 7, blk >> 3, t);
    gsync(bar + 5);
    // P6: a_s finalize + both MLPs + gate/unc + combine (8 blocks)
    if (blk < 8) fin_body(aspart, out_b, spec_w1, spec_b1, spec_w2, spec_b2,
                          spat_w1, spat_b1, spat_w2, spat_b2,
                          gate_w, gate_b, unc_w, unc_b, out, blk, t);
}

// ---------------- launcher ----------------
extern "C" void kernel_launch(void* const* d_in, const int* in_sizes, int n_in,
                              void* d_out, int out_size, void* d_ws, size_t ws_size,
                              hipStream_t stream)
{
    (void)in_sizes; (void)n_in; (void)out_size; (void)ws_size;
    const float* c2 = (const float*)d_in[0];
    const float* c3 = (const float*)d_in[1];
    const float* c4 = (const float*)d_in[2];
    const float* c5 = (const float*)d_in[3];
    const float* lat_w0 = (const float*)d_in[4];
    const float* lat_b0 = (const float*)d_in[5];
    const float* lat_w1 = (const float*)d_in[6];
    const float* lat_b1 = (const float*)d_in[7];
    const float* lat_w2 = (const float*)d_in[8];
    const float* lat_b2 = (const float*)d_in[9];
    const float* lat_w3 = (const float*)d_in[10];
    const float* lat_b3 = (const float*)d_in[11];
    const float* sp_w1 = (const float*)d_in[12];
    const float* sp_b1 = (const float*)d_in[13];
    const float* sp_w2 = (const float*)d_in[14];
    const float* sp_b2 = (const float*)d_in[15];
    const float* qkv_w = (const float*)d_in[16];
    const float* qkv_b = (const float*)d_in[17];
    const float* proj_w = (const float*)d_in[18];
    const float* proj_b = (const float*)d_in[19];
    const float* gat_W = (const float*)d_in[20];
    const float* gat_a = (const float*)d_in[21];
    const float* out_w = (const float*)d_in[22];
    const float* out_b = (const float*)d_in[23];
    const float* label_emb = (const float*)d_in[24];
    const float* spec_w1 = (const float*)d_in[25];
    const float* spec_b1 = (const float*)d_in[26];
    const float* spec_w2 = (const float*)d_in[27];
    const float* spec_b2 = (const float*)d_in[28];
    const float* spat_w1 = (const float*)d_in[29];
    const float* spat_b1 = (const float*)d_in[30];
    const float* spat_w2 = (const float*)d_in[31];
    const float* spat_b2 = (const float*)d_in[32];
    const float* gate_w = (const float*)d_in[33];
    const float* gate_b = (const float*)d_in[34];
    const float* unc_w = (const float*)d_in[35];
    const float* unc_b = (const float*)d_in[36];

    float* out = (float*)d_out;
    float* ws = (float*)d_ws;

    // workspace layout (floats); later phases reuse dead regions
    float* pf0    = ws + 0;        // 401408
    float* pf1    = ws + 401408;
    float* pf2    = ws + 1204224;
    float* pf3    = ws + 2809856;  // ends 6021120
    float* pooled = ws + 6021120;  // 16384
    float* swpart = ws + 6039552;  // 32768
    float* qkv    = ws + 0;        // reuses pf0/pf1 (dead after lateral)
    float* S      = ws + 1204224;  // reuses pf2/pf3
    float* xo     = ws + 3662848;  // 401408
    float* lf     = ws + 4064256;  // 163840 (ends 4228096)
    float* Wa     = ws + 4228096;  // 2048
    float* xopart = ws + 4230144;  // 14336
    float* gpart  = ws + 4244480;  // 8192
    float* s12    = ws + 4252672;  // 5120
    float* hm     = ws + 4265984;  // 8192
    float* aspart = ws + 4298752;  // 32768 (ends 4331520)
    float* xtok   = ws + 6106112;  // 401408 (ends 6507520)
    unsigned* bar = (unsigned*)(ws + 6507776);  // 8 grid-barrier counters

    float* swp  = out + 2568;  // sw [8,4] (output 5)
    float* atts = out + 2600;  // atts [4,8,80,80] (output 6)

    // 1. ALL pools + c5 mean in one dispatch (also zeroes bar counters)
    pool_all<<<27616, 256, 0, stream>>>(c2, c3, c4, c5, pf0, pf1, pf2, pf3, pooled, bar);
    // 2. scale weights + bias-initialized xtok
    sw_part<<<dim3(8, 8), 512, 0, stream>>>(pooled, sp_w1, swpart);
    sw_fin<<<8, 512, 0, stream>>>(swpart, sp_b1, sp_w2, sp_b2,
                                  lat_b0, lat_b1, lat_b2, lat_b3, swp, xtok);
    // 3. lateral projection + sw combine -> x tokens [1568,256]
    lateral_slice<<<dim3(196, 8), 256, 0, stream>>>(pf0, pf1, pf2, pf3,
                                                    lat_w0, lat_w1, lat_w2, lat_w3,
                                                    swp, xtok);
    // 4. qkv = x @ qkv_w + qkv_b : [1568,768]
    gemm_kernel<true><<<dim3(49 * 12, 1, 1), 256, 0, stream>>>(
        xtok, 256, 0, 0, qkv_w, 768, 0, 0, qkv, 768, 0, 0,
        qkv_b, 1568, 768, 256, 1.f, 49);
    // 5. S = q @ k^T * hd^-0.5, per (b,h) : [64,196,196]
    gemm_kernel<false><<<dim3(7 * 4, 8, 8), 256, 0, stream>>>(
        qkv, 768, 150528, 32, qkv + 256, 768, 150528, 32,
        S, 196, 307328, 38416, nullptr, 196, 196, 32, 0.17677669529663687f, 7);
    // 6. row softmax on S (in place)
    attn_softmax<<<3136, 256, 0, stream>>>(S);
    // 7. xo = P @ v : [1568,256] (head-concat layout)
    gemm_kernel<true><<<dim3(7, 8, 8), 256, 0, stream>>>(
        S, 196, 307328, 38416, qkv + 512, 768, 150528, 32,
        xo, 256, 50176, 32, nullptr, 196, 32, 196, 1.f, 7);
    // 8. everything after xo: ONE persistent kernel with 6 grid syncs
    tail_coop<<<640, 256, 0, stream>>>(
        xo, proj_w, proj_b, gat_W, gat_a, label_emb, out_w, out_b,
        spec_w1, spec_b1, spec_w2, spec_b2,
        spat_w1, spat_b1, spat_w2, spat_b2,
        gate_w, gate_b, unc_w, unc_b,
        xopart, gpart, Wa, lf, s12, atts, hm, aspart, out, bar);
}

// Round 2
// 543.144 us; speedup vs baseline: 1.4340x; 1.4340x over previous
//
#include <hip/hip_runtime.h>
#include <math.h>

typedef __attribute__((ext_vector_type(8))) short bshort8;
typedef __attribute__((ext_vector_type(4))) float f32x4;

#define DI __device__ __forceinline__

DI unsigned short f2bf(float x) {
    unsigned int u = __builtin_bit_cast(unsigned int, x);
    u += 0x7fffu + ((u >> 16) & 1u);
    return (unsigned short)(u >> 16);
}

DI bshort8 pack8(const float* v) {
    bshort8 r;
    #pragma unroll
    for (int j = 0; j < 8; j++) r[j] = (short)f2bf(v[j]);
    return r;
}

DI f32x4 mfma16(bshort8 a, bshort8 b, f32x4 c) {
    return __builtin_amdgcn_mfma_f32_16x16x32_bf16(a, b, c, 0, 0, 0);
}

// ---- composite (bilinear resize N->112, align_corners=False) + 8x8 avgpool stencils ----
__device__ const float W14[14][3] = {
    {0.875f, 0.125f, 0.f},
    {0.125f, 0.75f, 0.125f}, {0.125f, 0.75f, 0.125f}, {0.125f, 0.75f, 0.125f},
    {0.125f, 0.75f, 0.125f}, {0.125f, 0.75f, 0.125f}, {0.125f, 0.75f, 0.125f},
    {0.125f, 0.75f, 0.125f}, {0.125f, 0.75f, 0.125f}, {0.125f, 0.75f, 0.125f},
    {0.125f, 0.75f, 0.125f}, {0.125f, 0.75f, 0.125f}, {0.125f, 0.75f, 0.125f},
    {0.125f, 0.875f, 0.f}};
__device__ const float W28[14][4] = {
    {0.5f, 0.4375f, 0.0625f, 0.f},
    {0.0625f, 0.4375f, 0.4375f, 0.0625f}, {0.0625f, 0.4375f, 0.4375f, 0.0625f},
    {0.0625f, 0.4375f, 0.4375f, 0.0625f}, {0.0625f, 0.4375f, 0.4375f, 0.0625f},
    {0.0625f, 0.4375f, 0.4375f, 0.0625f}, {0.0625f, 0.4375f, 0.4375f, 0.0625f},
    {0.0625f, 0.4375f, 0.4375f, 0.0625f}, {0.0625f, 0.4375f, 0.4375f, 0.0625f},
    {0.0625f, 0.4375f, 0.4375f, 0.0625f}, {0.0625f, 0.4375f, 0.4375f, 0.0625f},
    {0.0625f, 0.4375f, 0.4375f, 0.0625f}, {0.0625f, 0.4375f, 0.4375f, 0.0625f},
    {0.0625f, 0.4375f, 0.5f, 0.f}};
__device__ const float W56[14][6] = {
    {0.25f, 0.25f, 0.25f, 0.21875f, 0.03125f, 0.f},
    {0.03125f, 0.21875f, 0.25f, 0.25f, 0.21875f, 0.03125f},
    {0.03125f, 0.21875f, 0.25f, 0.25f, 0.21875f, 0.03125f},
    {0.03125f, 0.21875f, 0.25f, 0.25f, 0.21875f, 0.03125f},
    {0.03125f, 0.21875f, 0.25f, 0.25f, 0.21875f, 0.03125f},
    {0.03125f, 0.21875f, 0.25f, 0.25f, 0.21875f, 0.03125f},
    {0.03125f, 0.21875f, 0.25f, 0.25f, 0.21875f, 0.03125f},
    {0.03125f, 0.21875f, 0.25f, 0.25f, 0.21875f, 0.03125f},
    {0.03125f, 0.21875f, 0.25f, 0.25f, 0.21875f, 0.03125f},
    {0.03125f, 0.21875f, 0.25f, 0.25f, 0.21875f, 0.03125f},
    {0.03125f, 0.21875f, 0.25f, 0.25f, 0.21875f, 0.03125f},
    {0.03125f, 0.21875f, 0.25f, 0.25f, 0.21875f, 0.03125f},
    {0.03125f, 0.21875f, 0.25f, 0.25f, 0.21875f, 0.03125f},
    {0.03125f, 0.21875f, 0.25f, 0.25f, 0.25f, 0.f}};

// -------- pooled-feature bodies; pf layout [cin][1568], col = b*196 + r --------
template <int N, int C, int TAPS>
DI void pool_body(const float* __restrict__ src, float* __restrict__ dst,
                  unsigned blk, unsigned t)
{
    unsigned id = blk * 256u + t;
    unsigned p = id / 196u;
    unsigned r = id - p * 196u;
    unsigned ti = r / 14u, tj = r - ti * 14u;
    unsigned b = p / C, cin = p - b * C;
    const float* plane = src + (size_t)p * (N * N);
    float acc = 0.f;
    if constexpr (N == 112) {
        const float4* p4 = (const float4*)(plane + (size_t)(ti * 8) * 112 + tj * 8);
        #pragma unroll
        for (int i = 0; i < 8; i++) {
            float4 u = p4[i * 28];
            float4 v = p4[i * 28 + 1];
            acc += (u.x + u.y) + (u.z + u.w) + (v.x + v.y) + (v.z + v.w);
        }
        acc *= (1.f / 64.f);
    } else {
        constexpr int STRIDE = N / 14;
        const float (*WT)[TAPS] = (N == 14) ? (const float (*)[TAPS])W14
                                : (N == 28) ? (const float (*)[TAPS])W28
                                            : (const float (*)[TAPS])W56;
        int hs = (int)(STRIDE * ti) - 1; if (hs < 0) hs = 0;
        int ws = (int)(STRIDE * tj) - 1; if (ws < 0) ws = 0;
        float wh[TAPS], ww[TAPS];
        #pragma unroll
        for (int i = 0; i < TAPS; i++) { wh[i] = WT[ti][i]; ww[i] = WT[tj][i]; }
        #pragma unroll
        for (int i = 0; i < TAPS; i++) {
            int hi = hs + i; if (hi > N - 1) hi = N - 1;
            const float* row = plane + (size_t)hi * N;
            float rs = 0.f;
            #pragma unroll
            for (int j = 0; j < TAPS; j++) {
                int wj = ws + j; if (wj > N - 1) wj = N - 1;
                rs += ww[j] * row[wj];
            }
            acc += wh[i] * rs;
        }
    }
    dst[(size_t)cin * 1568 + b * 196 + r] = acc;
}

DI void c5_mean_body(const float* __restrict__ c5, float* __restrict__ pooled,
                     unsigned blk, unsigned t)
{
    int wid = t >> 6, lane = t & 63;
    int p = blk * 4 + wid;
    const float* plane = c5 + (size_t)p * 196;
    float v = plane[lane] + plane[64 + lane] + plane[128 + lane];
    if (lane < 4) v += plane[192 + lane];
    #pragma unroll
    for (int off = 32; off > 0; off >>= 1) v += __shfl_xor(v, off, 64);
    if (lane == 0) pooled[p] = v * (1.f / 196.f);
}

// -------- K1: all four scale pools + c5 mean in ONE dispatch (block-range split) --------
__global__ __launch_bounds__(256) void pool_all(
    const float* __restrict__ c2, const float* __restrict__ c3,
    const float* __restrict__ c4, const float* __restrict__ c5,
    float* __restrict__ pf0, float* __restrict__ pf1,
    float* __restrict__ pf2, float* __restrict__ pf3,
    float* __restrict__ pooled, unsigned* __restrict__ flags)
{
    unsigned bx = blockIdx.x, t = threadIdx.x;
    if (bx == 27615u && t < 128u) flags[t] = 0u;   // zero team-barrier flags for tail_team
    if (bx < 1568u)       pool_body<112, 256, 8>(c2, pf0, bx, t);
    else if (bx < 4704u)  pool_body<56, 512, 6>(c3, pf1, bx - 1568u, t);
    else if (bx < 10976u) pool_body<28, 1024, 4>(c4, pf2, bx - 4704u, t);
    else if (bx < 23520u) pool_body<14, 2048, 3>(c5, pf3, bx - 10976u, t);
    else                  c5_mean_body(c5, pooled, bx - 23520u, t);
}

// -------- K2a: partial GEMV for sw MLP layer 1 (split-K) + hoisted Wa (y>=8) --------
__global__ __launch_bounds__(512) void sw_part(
    const float* __restrict__ pooled, const float* __restrict__ sp_w1,
    float* __restrict__ partial,
    const float* __restrict__ gat_W, const float* __restrict__ gat_a,
    float* __restrict__ Wa)
{
    int t = threadIdx.x;
    if (blockIdx.y >= 8) {
        // Wa[h][which][c] = dot(gat_W[h][c][:], a_which); 16 blocks, one (h,q) each
        int e = (blockIdx.y - 8) * 8 + blockIdx.x;   // [0,16)
        int h = e >> 2, q = e & 3;
        __shared__ float a1[256], a2[256];
        if (t < 256) { a1[t] = gat_a[h * 512 + t]; a2[t] = gat_a[h * 512 + 256 + t]; }
        __syncthreads();
        int w = t >> 6, lane = t & 63;
        #pragma unroll
        for (int ci = 0; ci < 8; ci++) {
            int c = q * 64 + w * 8 + ci;
            const float* row = gat_W + (size_t)h * 65536 + (size_t)c * 256;
            float p1 = 0.f, p2 = 0.f;
            #pragma unroll
            for (int jj = 0; jj < 4; jj++) {
                float v = row[lane + 64 * jj];
                p1 += v * a1[lane + 64 * jj];
                p2 += v * a2[lane + 64 * jj];
            }
            #pragma unroll
            for (int off = 32; off > 0; off >>= 1) {
                p1 += __shfl_xor(p1, off, 64);
                p2 += __shfl_xor(p2, off, 64);
            }
            if (lane == 0) { Wa[h * 512 + c] = p1; Wa[h * 512 + 256 + c] = p2; }
        }
        return;
    }
    int b = blockIdx.x, kc = blockIdx.y;
    __shared__ float ps[256];
    if (t < 256) ps[t] = pooled[b * 2048 + kc * 256 + t];
    __syncthreads();
    float acc = 0.f;
    const float* w = sp_w1 + (size_t)(kc * 256) * 512 + t;
    #pragma unroll 8
    for (int c = 0; c < 256; c++) acc += ps[c] * w[(size_t)c * 512];
    partial[((size_t)b * 8 + kc) * 512 + t] = acc;
}

// -------- K2b: finish sw MLP + write bias-initialized xtok --------
__global__ __launch_bounds__(512) void sw_fin(
    const float* __restrict__ partial, const float* __restrict__ sp_b1,
    const float* __restrict__ sp_w2, const float* __restrict__ sp_b2,
    const float* __restrict__ lb0, const float* __restrict__ lb1,
    const float* __restrict__ lb2, const float* __restrict__ lb3,
    float* __restrict__ sw_out, float* __restrict__ xtok)
{
    int b = blockIdx.x, t = threadIdx.x;
    __shared__ float h[512];
    __shared__ float s4s[4];
    __shared__ float swl[4];
    __shared__ float bf_s[256];
    float a = sp_b1[t];
    #pragma unroll
    for (int kc = 0; kc < 8; kc++) a += partial[((size_t)b * 8 + kc) * 512 + t];
    h[t] = fmaxf(a, 0.f);
    __syncthreads();
    int wv = t >> 6, lane = t & 63;
    if (wv < 4) {
        float acc = 0.f;
        #pragma unroll
        for (int i = 0; i < 8; i++) {
            int idx = lane + 64 * i;
            acc += h[idx] * sp_w2[idx * 4 + wv];
        }
        #pragma unroll
        for (int off = 32; off > 0; off >>= 1) acc += __shfl_xor(acc, off, 64);
        if (lane == 0) s4s[wv] = acc + sp_b2[wv];
    }
    __syncthreads();
    if (t == 0) {
        float mx = fmaxf(fmaxf(s4s[0], s4s[1]), fmaxf(s4s[2], s4s[3]));
        float e0 = expf(s4s[0] - mx), e1 = expf(s4s[1] - mx);
        float e2 = expf(s4s[2] - mx), e3 = expf(s4s[3] - mx);
        float inv = 1.f / (e0 + e1 + e2 + e3);
        swl[0] = e0 * inv; swl[1] = e1 * inv; swl[2] = e2 * inv; swl[3] = e3 * inv;
        for (int o = 0; o < 4; o++) sw_out[b * 4 + o] = swl[o];
    }
    __syncthreads();
    if (t < 256)
        bf_s[t] = swl[0] * lb0[t] + swl[1] * lb1[t] + swl[2] * lb2[t] + swl[3] * lb3[t];
    __syncthreads();
    int c = t & 255, half = t >> 8;
    float bv = bf_s[c];
    float* xb = xtok + (size_t)b * 196 * 256 + c;
    for (int r = half; r < 196; r += 2) xb[(size_t)r * 256] = bv;
}

// -------- K3: lateral projection, fragment-direct staging, 8 K-slices --------
__global__ __launch_bounds__(256) void lateral_slice(
    const float* __restrict__ pf0, const float* __restrict__ pf1,
    const float* __restrict__ pf2, const float* __restrict__ pf3,
    const float* __restrict__ w0, const float* __restrict__ w1,
    const float* __restrict__ w2, const float* __restrict__ w3,
    const float* __restrict__ sw, float* __restrict__ xtok)
{
    const int sArr[8]    = {0, 1, 2, 2, 3, 3, 3, 3};
    const int koffArr[8] = {0, 0, 0, 512, 0, 512, 1024, 1536};
    const int klenArr[8] = {256, 512, 512, 512, 512, 512, 512, 512};
    int sl = blockIdx.y;
    int s = sArr[sl], koff = koffArr[sl], klen = klenArr[sl];
    const float* pf = (s == 0) ? pf0 : (s == 1) ? pf1 : (s == 2) ? pf2 : pf3;
    const float* W  = (s == 0) ? w0  : (s == 1) ? w1  : (s == 2) ? w2  : w3;

    int mt = blockIdx.x % 49, nt = blockIdx.x / 49;
    int m0 = mt * 32, n0 = nt * 64;
    __shared__ alignas(16) unsigned short As[1024];
    __shared__ alignas(16) unsigned short Bs[2048];
    int t = threadIdx.x, lane = t & 63, wid = t >> 6;
    int wm = wid >> 1, wn = wid & 1;
    f32x4 acc0 = {0, 0, 0, 0}, acc1 = {0, 0, 0, 0};

    int f = t & 63;
    int mA = m0 + ((t >> 6) & 1) * 16 + (f & 15);   // t<128
    int kbA = (f >> 4) * 8;
    int nB = n0 + (t >> 6) * 16 + (f & 15);
    int kbB = (f >> 4) * 8;
    float swv = sw[(mA / 196) * 4 + s];

    float ar[8], br[8];
    auto loadA = [&](int k0) {
        if (t < 128) {
            const float* base = pf + (size_t)(koff + k0 + kbA) * 1568 + mA;
            #pragma unroll
            for (int j = 0; j < 8; j++) ar[j] = base[(size_t)j * 1568] * swv;
        }
    };
    auto loadB = [&](int k0) {
        const float* base = W + (size_t)(koff + k0 + kbB) * 256 + nB;
        #pragma unroll
        for (int j = 0; j < 8; j++) br[j] = base[(size_t)j * 256];
    };

    loadA(0); loadB(0);
    for (int k0 = 0; k0 < klen; k0 += 32) {
        if (t < 128) *(bshort8*)&As[(((t >> 6) & 1) * 512 + f * 8)] = pack8(ar);
        *(bshort8*)&Bs[((t >> 6) * 512 + f * 8)] = pack8(br);
        __syncthreads();
        if (k0 + 32 < klen) { loadA(k0 + 32); loadB(k0 + 32); }
        bshort8 av = *(const bshort8*)&As[wm * 512 + lane * 8];
        bshort8 bv0 = *(const bshort8*)&Bs[(wn * 2 + 0) * 512 + lane * 8];
        bshort8 bv1 = *(const bshort8*)&Bs[(wn * 2 + 1) * 512 + lane * 8];
        acc0 = mfma16(av, bv0, acc0);
        acc1 = mfma16(av, bv1, acc1);
        __syncthreads();
    }
    int col0 = n0 + wn * 32 + (lane & 15);
    int rbase = m0 + wm * 16 + ((lane >> 4) << 2);
    #pragma unroll
    for (int r = 0; r < 4; r++) {
        int m = rbase + r;
        atomicAdd(&xtok[(size_t)m * 256 + col0], acc0[r]);
        atomicAdd(&xtok[(size_t)m * 256 + col0 + 16], acc1[r]);
    }
}

// -------- generic bf16-MFMA GEMM --------
template <bool B_IS_KXN>
__global__ __launch_bounds__(256) void gemm_kernel(
    const float* __restrict__ Ab, int lda, long long sAy, long long sAz,
    const float* __restrict__ Bb, int ldb, long long sBy, long long sBz,
    float* __restrict__ Cb, int ldc, long long sCy, long long sCz,
    const float* __restrict__ bias, int M, int N, int K,
    float alpha, int mtiles)
{
    const float* A = Ab + blockIdx.y * sAy + blockIdx.z * sAz;
    const float* B = Bb + blockIdx.y * sBy + blockIdx.z * sBz;
    float* C = Cb + blockIdx.y * sCy + blockIdx.z * sCz;
    int mt = blockIdx.x % mtiles, nt = blockIdx.x / mtiles;
    int m0 = mt * 32, n0 = nt * 64;
    __shared__ alignas(16) unsigned short As[1024];
    __shared__ alignas(16) unsigned short Bs[2048];
    int t = threadIdx.x, lane = t & 63, wid = t >> 6;
    int wm = wid >> 1, wn = wid & 1;
    f32x4 acc0 = {0, 0, 0, 0}, acc1 = {0, 0, 0, 0};

    int f = t & 63;
    int mA = m0 + ((t >> 6) & 1) * 16 + (f & 15);   // t<128
    int kbA = (f >> 4) * 8;
    int nB = n0 + (t >> 6) * 16 + (f & 15);
    int kbB = (f >> 4) * 8;

    float ar[8], br[8];
    auto loadA = [&](int k0) {
        if (t < 128) {
            int kb = k0 + kbA;
            if (mA < M && kb + 8 <= K) {
                const float4* p = (const float4*)(A + (size_t)mA * lda + kb);
                float4 u = p[0], v = p[1];
                ar[0] = u.x; ar[1] = u.y; ar[2] = u.z; ar[3] = u.w;
                ar[4] = v.x; ar[5] = v.y; ar[6] = v.z; ar[7] = v.w;
            } else {
                #pragma unroll
                for (int j = 0; j < 8; j++) {
                    int k = kb + j;
                    ar[j] = (mA < M && k < K) ? A[(size_t)mA * lda + k] : 0.f;
                }
            }
        }
    };
    auto loadB = [&](int k0) {
        int kb = k0 + kbB;
        if constexpr (B_IS_KXN) {
            #pragma unroll
            for (int j = 0; j < 8; j++) {
                int k = kb + j;
                br[j] = (k < K && nB < N) ? B[(size_t)k * ldb + nB] : 0.f;
            }
        } else {
            if (nB < N && kb + 8 <= K) {
                const float4* p = (const float4*)(B + (size_t)nB * ldb + kb);
                float4 u = p[0], v = p[1];
                br[0] = u.x; br[1] = u.y; br[2] = u.z; br[3] = u.w;
                br[4] = v.x; br[5] = v.y; br[6] = v.z; br[7] = v.w;
            } else {
                #pragma unroll
                for (int j = 0; j < 8; j++) {
                    int k = kb + j;
                    br[j] = (nB < N && k < K) ? B[(size_t)nB * ldb + k] : 0.f;
                }
            }
        }
    };

    loadA(0); loadB(0);
    for (int k0 = 0; k0 < K; k0 += 32) {
        if (t < 128) *(bshort8*)&As[(((t >> 6) & 1) * 512 + f * 8)] = pack8(ar);
        *(bshort8*)&Bs[((t >> 6) * 512 + f * 8)] = pack8(br);
        __syncthreads();
        if (k0 + 32 < K) { loadA(k0 + 32); loadB(k0 + 32); }
        bshort8 av = *(const bshort8*)&As[wm * 512 + lane * 8];
        bshort8 bv0 = *(const bshort8*)&Bs[(wn * 2 + 0) * 512 + lane * 8];
        bshort8 bv1 = *(const bshort8*)&Bs[(wn * 2 + 1) * 512 + lane * 8];
        acc0 = mfma16(av, bv0, acc0);
        acc1 = mfma16(av, bv1, acc1);
        __syncthreads();
    }
    int col0 = n0 + wn * 32 + (lane & 15);
    int rbase = m0 + wm * 16 + ((lane >> 4) << 2);
    #pragma unroll
    for (int r = 0; r < 4; r++) {
        int m = rbase + r;
        if (m < M) {
            if (col0 < N) {
                float v = acc0[r] * alpha;
                if (bias) v += bias[col0];
                C[(size_t)m * ldc + col0] = v;
            }
            int c1 = col0 + 16;
            if (c1 < N) {
                float v = acc1[r] * alpha;
                if (bias) v += bias[c1];
                C[(size_t)m * ldc + c1] = v;
            }
        }
    }
}

// -------- attention softmax over rows of S [12544][196], in place --------
__global__ __launch_bounds__(256) void attn_softmax(float* __restrict__ S)
{
    int wid = threadIdx.x >> 6, lane = threadIdx.x & 63;
    size_t row = (size_t)blockIdx.x * 4 + wid;
    float* p = S + row * 196;
    float v0 = p[lane];
    float v1 = p[64 + lane];
    float v2 = p[128 + lane];
    float v3 = (lane < 4) ? p[192 + lane] : -1e30f;
    float mx = fmaxf(fmaxf(v0, v1), fmaxf(v2, v3));
    #pragma unroll
    for (int off = 32; off > 0; off >>= 1) mx = fmaxf(mx, __shfl_xor(mx, off, 64));
    float e0 = expf(v0 - mx), e1 = expf(v1 - mx), e2 = expf(v2 - mx);
    float e3 = (lane < 4) ? expf(v3 - mx) : 0.f;
    float sum = e0 + e1 + e2 + e3;
    #pragma unroll
    for (int off = 32; off > 0; off >>= 1) sum += __shfl_xor(sum, off, 64);
    float inv = 1.f / sum;
    p[lane] = e0 * inv;
    p[64 + lane] = e1 * inv;
    p[128 + lane] = e2 * inv;
    if (lane < 4) p[192 + lane] = e3 * inv;
}

// ================= tail: 8 independent teams of 8 blocks, flag barriers =================
// Arrival = one device-scope STORE per block (no RMW); wait = 8 lanes polling the
// team's 8 flag words with device-scope loads. threadfence release/acquire around it.

DI void team_sync(unsigned* __restrict__ flags, int fbase, int j, unsigned phase) {
    __syncthreads();
    __threadfence();                        // release: publish this block's writes
    if (threadIdx.x == 0)
        __hip_atomic_store(&flags[fbase + j], phase,
                           __ATOMIC_RELAXED, __HIP_MEMORY_SCOPE_AGENT);
    if (threadIdx.x < 8) {
        while (__hip_atomic_load(&flags[fbase + (int)threadIdx.x],
                                 __ATOMIC_RELAXED, __HIP_MEMORY_SCOPE_AGENT) < phase)
            __builtin_amdgcn_s_sleep(1);
    }
    __threadfence();                        // acquire: drop stale cached lines
    __syncthreads();
}

// 64 blocks x 256 threads; team b = blk>>3 (8 blocks), all per-b work, 8 barriers.
__global__ __launch_bounds__(256, 4) void tail_team(
    const float* __restrict__ xo, const float* __restrict__ proj_w,
    const float* __restrict__ proj_b,
    const float* __restrict__ gat_W, const float* __restrict__ lemb,
    const float* __restrict__ out_w, const float* __restrict__ out_b,
    const float* __restrict__ spec_w1, const float* __restrict__ spec_b1,
    const float* __restrict__ spec_w2, const float* __restrict__ spec_b2,
    const float* __restrict__ spat_w1, const float* __restrict__ spat_b1,
    const float* __restrict__ spat_w2, const float* __restrict__ spat_b2,
    const float* __restrict__ gate_w, const float* __restrict__ gate_b,
    const float* __restrict__ unc_w, const float* __restrict__ unc_b,
    const float* __restrict__ Wa,
    float* __restrict__ xopart, float* __restrict__ gctx,
    float* __restrict__ lf, float* __restrict__ s12, float* __restrict__ atts,
    float* __restrict__ hm, float* __restrict__ a_s, float* __restrict__ hb,
    float* __restrict__ fv, float* __restrict__ out,
    unsigned* __restrict__ flags)
{
    int blk = blockIdx.x, t = threadIdx.x;
    int b = blk >> 3, j = blk & 7;
    int lane = t & 63, w = t >> 6;
    int fbase = b * 16;
    __shared__ float sm[2304];

    // ---- P0: xo token-sum chunk j (196 tokens split 25x4 + 24x4) ----
    {
        const int st[8] = {0, 25, 50, 75, 100, 124, 148, 172};
        const int ln[8] = {25, 25, 25, 25, 24, 24, 24, 24};
        const float* base = xo + ((size_t)b * 196 + st[j]) * 256 + t;
        float s = 0.f;
        int nn = ln[j];
        for (int k = 0; k < nn; k++) s += base[(size_t)k * 256];
        xopart[(b * 8 + j) * 256 + t] = s;
    }
    team_sync(flags, fbase, j, 1);

    // ---- P1: gctx[b][n] = proj_b[n] + sum_k xm[k] proj_w[k][n], n in [32j,32j+32) ----
    {
        float s = 0.f;
        #pragma unroll
        for (int jj = 0; jj < 8; jj++) s += xopart[(b * 8 + jj) * 256 + t];
        sm[t] = s * (1.f / 196.f);          // xm
        __syncthreads();
        int nl = t & 31, ksub = t >> 5;
        int n = j * 32 + nl;
        float acc = 0.f;
        #pragma unroll 8
        for (int i = 0; i < 32; i++) {
            int k = ksub * 32 + i;
            acc += sm[k] * proj_w[(size_t)k * 256 + n];
        }
        __syncthreads();
        sm[256 + t] = acc;
        __syncthreads();
        if (t < 32) {
            float g = proj_b[j * 32 + t];
            #pragma unroll
            for (int s8 = 0; s8 < 8; s8++) g += sm[256 + t + 32 * s8];
            gctx[b * 256 + j * 32 + t] = g;
        }
    }
    team_sync(flags, fbase, j, 2);

    // ---- P2: lf rows l in [10j,10j+10) + s12 scores (8 pairs per row) ----
    {
        float gv = gctx[b * 256 + t];
        #pragma unroll
        for (int p8 = 0; p8 < 8; p8++) sm[p8 * 256 + t] = Wa[p8 * 256 + t];
        float* row = sm + 2048;
        __syncthreads();
        for (int r = 0; r < 10; r++) {
            int l = j * 10 + r;
            float v = lemb[l * 256 + t] + gv;
            lf[((size_t)b * 80 + l) * 256 + t] = v;
            row[t] = v;
            __syncthreads();
            #pragma unroll
            for (int pp = 0; pp < 2; pp++) {
                int pair = w * 2 + pp;
                float p = 0.f;
                #pragma unroll
                for (int jj = 0; jj < 4; jj++) {
                    int c = lane + 64 * jj;
                    p += row[c] * sm[pair * 256 + c];
                }
                #pragma unroll
                for (int off = 32; off > 0; off >>= 1) p += __shfl_xor(p, off, 64);
                if (lane == 0) s12[b * 640 + pair * 80 + l] = p;
            }
            __syncthreads();
        }
    }
    team_sync(flags, fbase, j, 3);

    // ---- P3: GAT row softmax -> atts; h = j>>1, rows i = (j&1)*40 + w*10 + it ----
    {
        int h = j >> 1;
        for (int it = 0; it < 10; it++) {
            int i = (j & 1) * 40 + w * 10 + it;
            float s1i = s12[b * 640 + (h * 2) * 80 + i];
            const float* s2 = s12 + b * 640 + (h * 2 + 1) * 80;
            float v0 = s1i + s2[lane]; v0 = v0 > 0.f ? v0 : 0.2f * v0;
            float v1 = -1e30f;
            if (lane < 16) { v1 = s1i + s2[64 + lane]; v1 = v1 > 0.f ? v1 : 0.2f * v1; }
            float mx = fmaxf(v0, v1);
            #pragma unroll
            for (int off = 32; off > 0; off >>= 1) mx = fmaxf(mx, __shfl_xor(mx, off, 64));
            float e0 = expf(v0 - mx), e1 = (lane < 16) ? expf(v1 - mx) : 0.f;
            float sum = e0 + e1;
            #pragma unroll
            for (int off = 32; off > 0; off >>= 1) sum += __shfl_xor(sum, off, 64);
            float inv = 1.f / sum;
            float* orow = atts + (size_t)h * 51200 + b * 6400 + i * 80;
            orow[lane] = e0 * inv;
            if (lane < 16) orow[64 + lane] = e1 * inv;
        }
    }
    team_sync(flags, fbase, j, 4);

    // ---- P4: am + amlf + hm; h = j>>1, half = j&1 writes hm cols half*128.. ----
    {
        int h = j >> 1, half = j & 1;
        if (t < 80) {
            const float* base = atts + (size_t)h * 51200 + b * 6400 + t;
            float acc = 0.f;
            #pragma unroll 8
            for (int l = 0; l < 80; l++) acc += base[l * 80];
            sm[t] = acc * (1.f / 80.f);     // am
        }
        __syncthreads();
        float acc = 0.f;
        const float* lfb = lf + (size_t)b * 80 * 256 + t;
        #pragma unroll 8
        for (int l = 0; l < 80; l++) acc += sm[l] * lfb[(size_t)l * 256];
        sm[80 + t] = acc;                   // av
        __syncthreads();
        int nl = t & 127, ksub = t >> 7;
        int n = half * 128 + nl;
        float acc2 = 0.f;
        #pragma unroll 8
        for (int i = 0; i < 128; i++) {
            int k = ksub * 128 + i;
            acc2 += sm[80 + k] * gat_W[(size_t)h * 65536 + (size_t)k * 256 + n];
        }
        sm[336 + t] = acc2;
        __syncthreads();
        if (t < 128)
            hm[b * 1024 + h * 256 + half * 128 + t] = sm[336 + t] + sm[336 + 128 + t];
    }
    team_sync(flags, fbase, j, 5);

    // ---- P5: a_s[b][n] = out_b[n] + sum_{k<1024} hm[b][k] out_w[k][n], n in [32j,..) ----
    {
        #pragma unroll
        for (int q4 = 0; q4 < 4; q4++) sm[q4 * 256 + t] = hm[b * 1024 + q4 * 256 + t];
        __syncthreads();
        int nl = t & 31, ksub = t >> 5;
        int n = j * 32 + nl;
        float acc = 0.f;
        #pragma unroll 8
        for (int i = 0; i < 128; i++) {
            int k = ksub * 128 + i;
            acc += sm[k] * out_w[(size_t)k * 256 + n];
        }
        __syncthreads();
        sm[1024 + t] = acc;
        __syncthreads();
        if (t < 32) {
            float s = out_b[j * 32 + t];
            #pragma unroll
            for (int s8 = 0; s8 < 8; s8++) s += sm[1024 + t + 32 * s8];
            a_s[b * 256 + j * 32 + t] = s;
        }
    }
    team_sync(flags, fbase, j, 6);

    // ---- P6: hidden = relu(a_s @ w1 + b1); unit u = j*32.. (j<4 spec, j>=4 spat) ----
    {
        sm[t] = a_s[b * 256 + t];
        __syncthreads();
        int which = j >> 2;
        int oo = (j & 3) * 32 + (t & 31);
        int ksub = t >> 5;
        const float* w1 = which ? spat_w1 : spec_w1;
        float acc = 0.f;
        #pragma unroll 8
        for (int i = 0; i < 32; i++) {
            int k = ksub * 32 + i;
            acc += sm[k] * w1[(size_t)k * 128 + oo];
        }
        __syncthreads();
        sm[256 + t] = acc;
        __syncthreads();
        if (t < 32) {
            int oo2 = (j & 3) * 32 + t;
            const float* b1 = which ? spat_b1 : spec_b1;
            float s = b1[oo2];
            #pragma unroll
            for (int s8 = 0; s8 < 8; s8++) s += sm[256 + t + 32 * s8];
            hb[b * 256 + which * 128 + oo2] = fmaxf(s, 0.f);
        }
    }
    team_sync(flags, fbase, j, 7);

    // ---- P7: head pre-activations fv[b][head][80]; outs u = j*40 + (t>>2), 4 thr/out ----
    {
        sm[t] = a_s[b * 256 + t];
        sm[256 + t] = hb[b * 256 + t];
        __syncthreads();
        if (t < 160) {
            int uu = t >> 2, sub = t & 3;
            int u = j * 40 + uu;
            int head = u / 80, o = u - head * 80;
            const float* wp; const float* bp; const float* src; int K;
            if (head == 0)      { wp = spec_w2; bp = spec_b2; src = sm + 256; K = 128; }
            else if (head == 1) { wp = spat_w2; bp = spat_b2; src = sm + 384; K = 128; }
            else if (head == 2) { wp = gate_w;  bp = gate_b;  src = sm;       K = 256; }
            else                { wp = unc_w;   bp = unc_b;   src = sm;       K = 256; }
            int K4 = K >> 2;
            float acc = 0.f;
            for (int i = 0; i < K4; i++) {
                int k = sub * K4 + i;
                acc += src[k] * wp[(size_t)k * 80 + o];
            }
            acc += __shfl_xor(acc, 1, 64);
            acc += __shfl_xor(acc, 2, 64);
            if (sub == 0) fv[b * 320 + u] = acc + bp[o];
        }
    }
    team_sync(flags, fbase, j, 8);

    // ---- P8: final combine (block j==0 of each team) ----
    if (j == 0) {
        if (t < 80) {
            float sp = fv[b * 320 + t], st2 = fv[b * 320 + 80 + t];
            float gz = fv[b * 320 + 160 + t], uz = fv[b * 320 + 240 + t];
            float g = 1.f / (1.f + expf(-gz));
            out[b * 80 + t] = g * sp + (1.f - g) * st2;
            out[640 + b * 80 + t] = sp;
            out[1280 + b * 80 + t] = st2;
            out[1920 + b * 80 + t] = g;
            sm[t] = log1pf(expf(uz)) + 1.f;
        }
        __syncthreads();
        if (t == 0) {
            float s = 0.f;
            for (int l = 0; l < 80; l++) s += sm[l];
            out[2560 + b] = 80.f / s;
        }
    }
}

// ---------------- launcher ----------------
extern "C" void kernel_launch(void* const* d_in, const int* in_sizes, int n_in,
                              void* d_out, int out_size, void* d_ws, size_t ws_size,
                              hipStream_t stream)
{
    (void)in_sizes; (void)n_in; (void)out_size; (void)ws_size;
    const float* c2 = (const float*)d_in[0];
    const float* c3 = (const float*)d_in[1];
    const float* c4 = (const float*)d_in[2];
    const float* c5 = (const float*)d_in[3];
    const float* lat_w0 = (const float*)d_in[4];
    const float* lat_b0 = (const float*)d_in[5];
    const float* lat_w1 = (const float*)d_in[6];
    const float* lat_b1 = (const float*)d_in[7];
    const float* lat_w2 = (const float*)d_in[8];
    const float* lat_b2 = (const float*)d_in[9];
    const float* lat_w3 = (const float*)d_in[10];
    const float* lat_b3 = (const float*)d_in[11];
    const float* sp_w1 = (const float*)d_in[12];
    const float* sp_b1 = (const float*)d_in[13];
    const float* sp_w2 = (const float*)d_in[14];
    const float* sp_b2 = (const float*)d_in[15];
    const float* qkv_w = (const float*)d_in[16];
    const float* qkv_b = (const float*)d_in[17];
    const float* proj_w = (const float*)d_in[18];
    const float* proj_b = (const float*)d_in[19];
    const float* gat_W = (const float*)d_in[20];
    const float* gat_a = (const float*)d_in[21];
    const float* out_w = (const float*)d_in[22];
    const float* out_b = (const float*)d_in[23];
    const float* label_emb = (const float*)d_in[24];
    const float* spec_w1 = (const float*)d_in[25];
    const float* spec_b1 = (const float*)d_in[26];
    const float* spec_w2 = (const float*)d_in[27];
    const float* spec_b2 = (const float*)d_in[28];
    const float* spat_w1 = (const float*)d_in[29];
    const float* spat_b1 = (const float*)d_in[30];
    const float* spat_w2 = (const float*)d_in[31];
    const float* spat_b2 = (const float*)d_in[32];
    const float* gate_w = (const float*)d_in[33];
    const float* gate_b = (const float*)d_in[34];
    const float* unc_w = (const float*)d_in[35];
    const float* unc_b = (const float*)d_in[36];

    float* out = (float*)d_out;
    float* ws = (float*)d_ws;

    // workspace layout (floats); later phases reuse dead regions
    float* pf0    = ws + 0;        // 401408
    float* pf1    = ws + 401408;
    float* pf2    = ws + 1204224;
    float* pf3    = ws + 2809856;  // ends 6021120
    float* pooled = ws + 6021120;  // 16384
    float* swpart = ws + 6039552;  // 32768
    float* qkv    = ws + 0;        // reuses pf0/pf1 (dead after lateral)
    float* S      = ws + 1204224;  // reuses pf2/pf3
    float* xo     = ws + 3662848;  // 401408 -> 4064256
    float* lf     = ws + 4064256;  // 163840 -> 4228096
    float* Wa     = ws + 4228096;  // 2048   -> 4230144
    float* xopart = ws + 4230144;  // 16384  -> 4246528
    float* gctx   = ws + 4246528;  // 2048   -> 4248576
    float* s12    = ws + 4248576;  // 5120   -> 4253696
    float* hm     = ws + 4253696;  // 8192   -> 4261888
    float* a_sb   = ws + 4261888;  // 2048   -> 4263936
    float* hbuf   = ws + 4263936;  // 2048   -> 4265984
    float* fvb    = ws + 4265984;  // 2560   -> 4268544
    float* xtok   = ws + 6106112;  // 401408 -> 6507520
    unsigned* flags = (unsigned*)(ws + 6507776);  // 128 words of team flags

    float* swp  = out + 2568;  // sw [8,4] (output 5)
    float* atts = out + 2600;  // atts [4,8,80,80] (output 6)

    // 1. ALL pools + c5 mean in one dispatch (also zeroes team flags)
    pool_all<<<27616, 256, 0, stream>>>(c2, c3, c4, c5, pf0, pf1, pf2, pf3, pooled, flags);
    // 2. scale-weight MLP partials + hoisted Wa (16 extra blocks)
    sw_part<<<dim3(8, 10), 512, 0, stream>>>(pooled, sp_w1, swpart, gat_W, gat_a, Wa);
    sw_fin<<<8, 512, 0, stream>>>(swpart, sp_b1, sp_w2, sp_b2,
                                  lat_b0, lat_b1, lat_b2, lat_b3, swp, xtok);
    // 3. lateral projection + sw combine -> x tokens [1568,256]
    lateral_slice<<<dim3(196, 8), 256, 0, stream>>>(pf0, pf1, pf2, pf3,
                                                    lat_w0, lat_w1, lat_w2, lat_w3,
                                                    swp, xtok);
    // 4. qkv = x @ qkv_w + qkv_b : [1568,768]
    gemm_kernel<true><<<dim3(49 * 12, 1, 1), 256, 0, stream>>>(
        xtok, 256, 0, 0, qkv_w, 768, 0, 0, qkv, 768, 0, 0,
        qkv_b, 1568, 768, 256, 1.f, 49);
    // 5. S = q @ k^T * hd^-0.5, per (b,h) : [64,196,196]
    gemm_kernel<false><<<dim3(7 * 4, 8, 8), 256, 0, stream>>>(
        qkv, 768, 150528, 32, qkv + 256, 768, 150528, 32,
        S, 196, 307328, 38416, nullptr, 196, 196, 32, 0.17677669529663687f, 7);
    // 6. row softmax on S (in place)
    attn_softmax<<<3136, 256, 0, stream>>>(S);
    // 7. xo = P @ v : [1568,256] (head-concat layout)
    gemm_kernel<true><<<dim3(7, 8, 8), 256, 0, stream>>>(
        S, 196, 307328, 38416, qkv + 512, 768, 150528, 32,
        xo, 256, 50176, 32, nullptr, 196, 32, 196, 1.f, 7);
    // 8. everything after xo: 8 teams x 8 blocks, team-local flag barriers
    tail_team<<<64, 256, 0, stream>>>(
        xo, proj_w, proj_b, gat_W, label_emb, out_w, out_b,
        spec_w1, spec_b1, spec_w2, spec_b2,
        spat_w1, spat_b1, spat_w2, spat_b2,
        gate_w, gate_b, unc_w, unc_b, Wa,
        xopart, gctx, lf, s12, atts, hm, a_sb, hbuf, fvb, out, flags);
}